// Round 7
// baseline (1452.357 us; speedup 1.0000x reference)
//
#include <hip/hip_runtime.h>
#include <hip/hip_bf16.h>
#include <math.h>

// Problem constants
#define GL 2
#define GH 128
#define GH2 256
#define GV 50257
#define GB 100
#define GT 50
#define GM 5000            // B*T rows
#define NT 393             // n tiles (128 wide): ceil(50257/128)
#define MT 40              // m tiles (128 tall): ceil(5000/128)

typedef __attribute__((ext_vector_type(4))) float f32x4;
typedef __attribute__((ext_vector_type(8))) short bf16x8;

// ---------------------------------------------------------------------------
// Kernel 1: GRU. One block per batch item (r2/r5-verified version).
// ---------------------------------------------------------------------------
__global__ __launch_bounds__(1024) void gru_kernel(
    const int* __restrict__ tok,        // (B,T)
    const float* __restrict__ emb,      // (V,H)
    const float* __restrict__ gate_k,   // (L,2H,2H)
    const float* __restrict__ gate_b,   // (L,2H)
    const float* __restrict__ cand_k,   // (L,2H,H)
    const float* __restrict__ cand_b,   // (L,H)
    float* __restrict__ out)            // (B*T,H)
{
    const int b = blockIdx.x;
    const int tid = threadIdx.x;

    __shared__ float xin[GH2];
    __shared__ float hs[2][GH];
    __shared__ float g[GH2];
    __shared__ float gpart[4][GH2];
    __shared__ float cpart[8][GH];

    if (tid < GH) { hs[0][tid] = 0.f; hs[1][tid] = 0.f; }
    __syncthreads();

    for (int t = 0; t < GT; ++t) {
        const int token = tok[b * GT + t];
        if (tid < GH) xin[tid] = emb[(size_t)token * GH + tid];

        for (int l = 0; l < GL; ++l) {
            if (tid >= GH && tid < GH2) xin[tid] = hs[l][tid - GH];
            __syncthreads();

            {   // gate
                const int j  = tid & 255;
                const int t4 = tid >> 8;
                const float* gcol = gate_k + (size_t)l * GH2 * GH2 + (size_t)(t4 * 64) * GH2 + j;
                const float* xv = xin + t4 * 64;
                float acc = 0.f;
                #pragma unroll 16
                for (int i = 0; i < 64; ++i) acc += xv[i] * gcol[(size_t)i * GH2];
                gpart[t4][j] = acc;
            }
            __syncthreads();
            if (tid < GH2) {
                float s = gpart[0][tid] + gpart[1][tid] + gpart[2][tid] + gpart[3][tid]
                        + gate_b[l * GH2 + tid];
                g[tid] = 1.f / (1.f + expf(-s));
            }
            __syncthreads();
            if (tid >= GH && tid < GH2) xin[tid] = g[tid - GH] * hs[l][tid - GH];
            __syncthreads();

            {   // cand
                const int j  = tid & 127;
                const int t8 = tid >> 7;
                const float* ccol = cand_k + (size_t)l * GH2 * GH + (size_t)(t8 * 32) * GH + j;
                const float* xv = xin + t8 * 32;
                float acc = 0.f;
                #pragma unroll 16
                for (int i = 0; i < 32; ++i) acc += xv[i] * ccol[(size_t)i * GH];
                cpart[t8][j] = acc;
            }
            __syncthreads();
            if (tid < GH) {
                float csum = 0.f;
                #pragma unroll
                for (int p = 0; p < 8; ++p) csum += cpart[p][tid];
                const float c = tanhf(csum + cand_b[l * GH + tid]);
                const float u = g[GH + tid];
                const float hn = u * hs[l][tid] + (1.f - u) * c;
                hs[l][tid] = hn;
                xin[tid] = hn;
                if (l == GL - 1) out[(size_t)(b * GT + t) * GH + tid] = hn;
            }
            __syncthreads();
        }
    }
}

// ---------------------------------------------------------------------------
// bf16 split helpers
// ---------------------------------------------------------------------------
__device__ __forceinline__ unsigned short f2bf(float x) {
    union { float f; unsigned u; } c; c.f = x;
    unsigned r = c.u + 0x7FFFu + ((c.u >> 16) & 1u);   // RNE
    return (unsigned short)(r >> 16);
}
__device__ __forceinline__ float bf2f(unsigned short b) {
    union { unsigned u; float f; } c; c.u = ((unsigned)b) << 16; return c.f;
}

// ---------------------------------------------------------------------------
// Kernel 2: prep — fp32 (rows x 128) -> staged XOR-swizzled bf16 chunks.
// chunk 0: hi(k0..63)  1: hi(k64..127)  2: lo(k0..63)  3: lo(k64..127)
// (r,k) stored at r*64 + (k ^ ((r&7)<<3)): linear global_load_lds then yields
// a bank-conflict-free swizzled LDS image (swizzle source + read, rule #21).
// ---------------------------------------------------------------------------
__global__ __launch_bounds__(256) void prep_kernel(
    const float* __restrict__ src, unsigned short* __restrict__ dst,
    int ntiles, int nrows)
{
    const int idx = blockIdx.x * 256 + threadIdx.x;
    if (idx >= ntiles * 4 * 128) return;
    const int r    = idx & 127;
    const int c    = idx >> 7;
    const int cs   = c & 3;
    const int tile = c >> 2;
    int row = tile * 128 + r; if (row > nrows - 1) row = nrows - 1;
    const float* s = src + (size_t)row * GH + (cs & 1) * 64;
    unsigned short* d = dst + (size_t)c * 8192 + r * 64;
    const bool lo = (cs >= 2);
    const int rx = r & 7;

    #pragma unroll
    for (int gq = 0; gq < 8; ++gq) {
        float x[8];
        *(float4*)(x)     = *(const float4*)(s + gq * 8);
        *(float4*)(x + 4) = *(const float4*)(s + gq * 8 + 4);
        unsigned u[4];
        #pragma unroll
        for (int q = 0; q < 4; ++q) {
            const float a0 = x[q * 2], a1 = x[q * 2 + 1];
            const unsigned short hi0 = f2bf(a0), hi1 = f2bf(a1);
            unsigned short h0, h1;
            if (lo) { h0 = f2bf(a0 - bf2f(hi0)); h1 = f2bf(a1 - bf2f(hi1)); }
            else    { h0 = hi0; h1 = hi1; }
            u[q] = (unsigned)h0 | ((unsigned)h1 << 16);
        }
        *(uint4*)(d + (size_t)((gq ^ rx) * 8)) = *(const uint4*)u;
    }
}

// ---------------------------------------------------------------------------
// Kernel 3: MFMA logits GEMM, K=384 bf16 (hi*hi + hi*lo + lo*hi), 128x128
// tile, 4 waves (r5 base). SINGLE change vs r5: double-buffered LDS with the
// T3-minimum 2-phase recipe (m230-V0): STAGE(next buf) issued BEFORE
// compute(cur), then ONE __syncthreads per step — its implicit vmcnt(0)
// drain lands AFTER ~500 cyc of ds_read+MFMA, so next-stage load latency
// hides under current compute instead of stalling cold.
//   s:      0      1      2      3      4      5
//   A:    hi k0  hi k1  hi k0  hi k1  lo k0  lo k1
//   W:    hi k0  hi k1  lo k0  lo k1  hi k0  hi k1
// ---------------------------------------------------------------------------
__global__ __launch_bounds__(256) void mfma_logits_kernel(
    const unsigned short* __restrict__ Ap, const unsigned short* __restrict__ Wp,
    const float* __restrict__ bias,
    float* __restrict__ logits, float* __restrict__ pmax, float* __restrict__ psum)
{
    __shared__ unsigned short ldsA[2][8192];
    __shared__ unsigned short ldsW[2][8192];
    __shared__ float sM[2][128];
    __shared__ float sS[2][128];

    const int bm  = blockIdx.x;     // m tile (fastest -> W-tile L2 locality)
    const int bt  = blockIdx.y;     // n tile
    const int tid = threadIdx.x;
    const int wid  = tid >> 6;
    const int lane = tid & 63;
    const int wm = wid >> 1, wn = wid & 1;
    const int l15 = lane & 15, l4 = lane >> 4;

    constexpr int amap[6] = {0, 1, 0, 1, 2, 3};
    constexpr int wmap[6] = {0, 1, 2, 3, 0, 1};

    f32x4 acc[4][4];
    #pragma unroll
    for (int i = 0; i < 4; ++i)
        #pragma unroll
        for (int j = 0; j < 4; ++j) acc[i][j] = (f32x4){0.f, 0.f, 0.f, 0.f};

#define STAGE(BUF, S)                                                                   \
    {                                                                                   \
        const unsigned short* ga = Ap + (size_t)(bm * 4 + amap[S]) * 8192 + wid * 2048 + lane * 8; \
        const unsigned short* gw = Wp + (size_t)(bt * 4 + wmap[S]) * 8192 + wid * 2048 + lane * 8; \
        _Pragma("unroll")                                                               \
        for (int i = 0; i < 4; ++i)                                                     \
            __builtin_amdgcn_global_load_lds(                                           \
                (const __attribute__((address_space(1))) void*)(ga + i * 512),          \
                (__attribute__((address_space(3))) void*)(&ldsA[BUF][wid * 2048 + i * 512]), 16, 0, 0); \
        _Pragma("unroll")                                                               \
        for (int i = 0; i < 4; ++i)                                                     \
            __builtin_amdgcn_global_load_lds(                                           \
                (const __attribute__((address_space(1))) void*)(gw + i * 512),          \
                (__attribute__((address_space(3))) void*)(&ldsW[BUF][wid * 2048 + i * 512]), 16, 0, 0); \
    }

    STAGE(0, 0);
    __syncthreads();

    #pragma unroll
    for (int s = 0; s < 6; ++s) {
        const int cur = s & 1;
        if (s < 5) STAGE((s + 1) & 1, s + 1);   // issue next-tile loads first

        #pragma unroll
        for (int ks = 0; ks < 2; ++ks) {
            bf16x8 af[4], bf[4];
            #pragma unroll
            for (int mi = 0; mi < 4; ++mi) {
                const int row = wm * 64 + mi * 16 + l15;
                const int off = row * 64 + ((ks * 32 + l4 * 8) ^ ((row & 7) << 3));
                af[mi] = *(const bf16x8*)&ldsA[cur][off];
            }
            #pragma unroll
            for (int nj = 0; nj < 4; ++nj) {
                const int row = wn * 64 + nj * 16 + l15;
                const int off = row * 64 + ((ks * 32 + l4 * 8) ^ ((row & 7) << 3));
                bf[nj] = *(const bf16x8*)&ldsW[cur][off];
            }
            #pragma unroll
            for (int mi = 0; mi < 4; ++mi)
                #pragma unroll
                for (int nj = 0; nj < 4; ++nj)
                    acc[mi][nj] = __builtin_amdgcn_mfma_f32_16x16x32_bf16(
                        af[mi], bf[nj], acc[mi][nj], 0, 0, 0);
        }
        __syncthreads();   // one barrier per step; drains the in-flight stage
    }
#undef STAGE

    // ---- epilogue: bias, store, per-(row, tile) softmax partials ----
    float bj[4]; bool nv[4];
    #pragma unroll
    for (int nj = 0; nj < 4; ++nj) {
        const int n = bt * 128 + wn * 64 + nj * 16 + l15;
        nv[nj] = (n < GV);
        bj[nj] = nv[nj] ? bias[n] : 0.f;
    }
    #pragma unroll
    for (int mi = 0; mi < 4; ++mi) {
        #pragma unroll
        for (int r = 0; r < 4; ++r) {
            const int rowb = wm * 64 + mi * 16 + l4 * 4 + r;
            const int m = bm * 128 + rowb;
            float v[4];
            #pragma unroll
            for (int nj = 0; nj < 4; ++nj) v[nj] = acc[mi][nj][r] + bj[nj];
            if (m < GM) {
                #pragma unroll
                for (int nj = 0; nj < 4; ++nj)
                    if (nv[nj])
                        logits[(size_t)m * GV + (bt * 128 + wn * 64 + nj * 16 + l15)] = v[nj];
            }
            float mx = -INFINITY;
            #pragma unroll
            for (int nj = 0; nj < 4; ++nj) if (nv[nj]) mx = fmaxf(mx, v[nj]);
            #pragma unroll
            for (int d = 1; d < 16; d <<= 1) mx = fmaxf(mx, __shfl_xor(mx, d));
            float se = 0.f;
            #pragma unroll
            for (int nj = 0; nj < 4; ++nj) if (nv[nj]) se += __expf(v[nj] - mx);
            #pragma unroll
            for (int d = 1; d < 16; d <<= 1) se += __shfl_xor(se, d);
            if (l15 == 0) { sM[wn][rowb] = mx; sS[wn][rowb] = se; }
        }
    }
    __syncthreads();
    if (tid < 128) {
        const int m = bm * 128 + tid;
        if (m < GM) {
            const float m0 = sM[0][tid], m1 = sM[1][tid];
            const float M = fmaxf(m0, m1);
            const float S = sS[0][tid] * __expf(m0 - M) + sS[1][tid] * __expf(m1 - M);
            pmax[(size_t)m * NT + bt] = M;
            psum[(size_t)m * NT + bt] = S;
        }
    }
}

// ---------------------------------------------------------------------------
// Kernel 4: merge per-tile (max,sum) -> per-row (max, 1/sum). 1 wave per row.
// ---------------------------------------------------------------------------
__global__ __launch_bounds__(64) void reduce_kernel(
    const float* __restrict__ pmax, const float* __restrict__ psum,
    float* __restrict__ rowM, float* __restrict__ rowInvS)
{
    const int m = blockIdx.x;
    const int lane = threadIdx.x;
    float M = -INFINITY, S = 0.f;
    for (int t = lane; t < NT; t += 64) {
        const float m2 = pmax[(size_t)m * NT + t];
        const float s2 = psum[(size_t)m * NT + t];
        const float nM = fmaxf(M, m2);
        S = S * expf(M - nM) + s2 * expf(m2 - nM);
        M = nM;
    }
    #pragma unroll
    for (int d = 1; d < 64; d <<= 1) {
        const float m2 = __shfl_xor(M, d);
        const float s2 = __shfl_xor(S, d);
        const float nM = fmaxf(M, m2);
        S = S * expf(M - nM) + s2 * expf(m2 - nM);
        M = nM;
    }
    if (lane == 0) { rowM[m] = M; rowInvS[m] = 1.f / S; }
}

// ---------------------------------------------------------------------------
// Kernel 5: probs = exp(logits - M) * invS. float4 grid-stride.
// ---------------------------------------------------------------------------
__global__ __launch_bounds__(256) void probs_kernel(
    const float* __restrict__ logits,
    const float* __restrict__ rowM, const float* __restrict__ rowInvS,
    float* __restrict__ probs)
{
    const float4* L4 = reinterpret_cast<const float4*>(logits);
    float4* P4 = reinterpret_cast<float4*>(probs);
    const int n4 = (int)(((long long)GM * GV) / 4);
    const int stride = gridDim.x * blockDim.x;
    for (int i = blockIdx.x * blockDim.x + threadIdx.x; i < n4; i += stride) {
        const float4 v = L4[i];
        const int base = i * 4;
        const int m0 = base / GV;
        const int m3 = (base + 3) / GV;
        float4 o;
        if (m0 == m3) {
            const float M = rowM[m0], Is = rowInvS[m0];
            o.x = __expf(v.x - M) * Is;
            o.y = __expf(v.y - M) * Is;
            o.z = __expf(v.z - M) * Is;
            o.w = __expf(v.w - M) * Is;
        } else {
            const int ma = base / GV, mb = (base + 1) / GV;
            const int mc = (base + 2) / GV, md = (base + 3) / GV;
            o.x = __expf(v.x - rowM[ma]) * rowInvS[ma];
            o.y = __expf(v.y - rowM[mb]) * rowInvS[mb];
            o.z = __expf(v.z - rowM[mc]) * rowInvS[mc];
            o.w = __expf(v.w - rowM[md]) * rowInvS[md];
        }
        P4[i] = o;
    }
}

// ---------------------------------------------------------------------------
extern "C" void kernel_launch(void* const* d_in, const int* in_sizes, int n_in,
                              void* d_out, int out_size, void* d_ws, size_t ws_size,
                              hipStream_t stream) {
    const int*   tok    = (const int*)d_in[0];
    const float* emb    = (const float*)d_in[1];
    const float* gate_k = (const float*)d_in[2];
    const float* gate_b = (const float*)d_in[3];
    const float* cand_k = (const float*)d_in[4];
    const float* cand_b = (const float*)d_in[5];
    const float* W      = (const float*)d_in[6];
    const float* bias   = (const float*)d_in[7];

    float* logits = (float*)d_out;
    float* probs  = logits + (size_t)GM * GV;

    float* ws = (float*)d_ws;
    float* gruout = ws;                                        // 640,000 f32
    unsigned short* Ap = (unsigned short*)(gruout + 640000);   // 40*4*8192 bf16
    unsigned short* Wp = Ap + (size_t)MT * 4 * 8192;           // 393*4*8192 bf16
    float* pmax    = (float*)(Wp + (size_t)NT * 4 * 8192);
    float* psum    = pmax + (size_t)GM * NT;
    float* rowM    = psum + (size_t)GM * NT;
    float* rowInvS = rowM + GM;

    gru_kernel<<<GB, 1024, 0, stream>>>(tok, emb, gate_k, gate_b, cand_k, cand_b, gruout);

    prep_kernel<<<(MT * 4 * 128 + 255) / 256, 256, 0, stream>>>(gruout, Ap, MT, GM);
    prep_kernel<<<(NT * 4 * 128 + 255) / 256, 256, 0, stream>>>(W, Wp, NT, GV);

    dim3 g2(MT, NT);   // m-tile fastest: W-tile L2/L3 locality
    mfma_logits_kernel<<<g2, 256, 0, stream>>>(Ap, Wp, bias, logits, pmax, psum);

    reduce_kernel<<<GM, 64, 0, stream>>>(pmax, psum, rowM, rowInvS);

    probs_kernel<<<4096, 256, 0, stream>>>(logits, rowM, rowInvS, probs);
}

// Round 8
// 1353.285 us; speedup vs baseline: 1.0732x; 1.0732x over previous
//
#include <hip/hip_runtime.h>
#include <hip/hip_bf16.h>
#include <math.h>

// Problem constants
#define GL 2
#define GH 128
#define GH2 256
#define GV 50257
#define GB 100
#define GT 50
#define GM 5000            // B*T rows
#define NT 393             // n tiles (128 wide): ceil(50257/128)
#define MT 40              // m tiles (128 tall): ceil(5000/128)

typedef __attribute__((ext_vector_type(4))) float f32x4;
typedef __attribute__((ext_vector_type(8))) short bf16x8;

// ---------------------------------------------------------------------------
// Kernel 1: GRU. One block per batch item (r2/r5-verified version).
// ---------------------------------------------------------------------------
__global__ __launch_bounds__(1024) void gru_kernel(
    const int* __restrict__ tok,        // (B,T)
    const float* __restrict__ emb,      // (V,H)
    const float* __restrict__ gate_k,   // (L,2H,2H)
    const float* __restrict__ gate_b,   // (L,2H)
    const float* __restrict__ cand_k,   // (L,2H,H)
    const float* __restrict__ cand_b,   // (L,H)
    float* __restrict__ out)            // (B*T,H)
{
    const int b = blockIdx.x;
    const int tid = threadIdx.x;

    __shared__ float xin[GH2];
    __shared__ float hs[2][GH];
    __shared__ float g[GH2];
    __shared__ float gpart[4][GH2];
    __shared__ float cpart[8][GH];

    if (tid < GH) { hs[0][tid] = 0.f; hs[1][tid] = 0.f; }
    __syncthreads();

    for (int t = 0; t < GT; ++t) {
        const int token = tok[b * GT + t];
        if (tid < GH) xin[tid] = emb[(size_t)token * GH + tid];

        for (int l = 0; l < GL; ++l) {
            if (tid >= GH && tid < GH2) xin[tid] = hs[l][tid - GH];
            __syncthreads();

            {   // gate
                const int j  = tid & 255;
                const int t4 = tid >> 8;
                const float* gcol = gate_k + (size_t)l * GH2 * GH2 + (size_t)(t4 * 64) * GH2 + j;
                const float* xv = xin + t4 * 64;
                float acc = 0.f;
                #pragma unroll 16
                for (int i = 0; i < 64; ++i) acc += xv[i] * gcol[(size_t)i * GH2];
                gpart[t4][j] = acc;
            }
            __syncthreads();
            if (tid < GH2) {
                float s = gpart[0][tid] + gpart[1][tid] + gpart[2][tid] + gpart[3][tid]
                        + gate_b[l * GH2 + tid];
                g[tid] = 1.f / (1.f + expf(-s));
            }
            __syncthreads();
            if (tid >= GH && tid < GH2) xin[tid] = g[tid - GH] * hs[l][tid - GH];
            __syncthreads();

            {   // cand
                const int j  = tid & 127;
                const int t8 = tid >> 7;
                const float* ccol = cand_k + (size_t)l * GH2 * GH + (size_t)(t8 * 32) * GH + j;
                const float* xv = xin + t8 * 32;
                float acc = 0.f;
                #pragma unroll 16
                for (int i = 0; i < 32; ++i) acc += xv[i] * ccol[(size_t)i * GH];
                cpart[t8][j] = acc;
            }
            __syncthreads();
            if (tid < GH) {
                float csum = 0.f;
                #pragma unroll
                for (int p = 0; p < 8; ++p) csum += cpart[p][tid];
                const float c = tanhf(csum + cand_b[l * GH + tid]);
                const float u = g[GH + tid];
                const float hn = u * hs[l][tid] + (1.f - u) * c;
                hs[l][tid] = hn;
                xin[tid] = hn;
                if (l == GL - 1) out[(size_t)(b * GT + t) * GH + tid] = hn;
            }
            __syncthreads();
        }
    }
}

// ---------------------------------------------------------------------------
// bf16 split helpers
// ---------------------------------------------------------------------------
__device__ __forceinline__ unsigned short f2bf(float x) {
    union { float f; unsigned u; } c; c.f = x;
    unsigned r = c.u + 0x7FFFu + ((c.u >> 16) & 1u);   // RNE
    return (unsigned short)(r >> 16);
}
__device__ __forceinline__ float bf2f(unsigned short b) {
    union { unsigned u; float f; } c; c.u = ((unsigned)b) << 16; return c.f;
}

// ---------------------------------------------------------------------------
// Kernel 2: prep — fp32 (rows x 128) -> staged XOR-swizzled bf16 chunks.
// chunk 0: hi(k0..63)  1: hi(k64..127)  2: lo(k0..63)  3: lo(k64..127)
// (r,k) stored at r*64 + (k ^ ((r&7)<<3)): linear global_load_lds then yields
// a bank-conflict-free swizzled LDS image (swizzle source + read, rule #21).
// ---------------------------------------------------------------------------
__global__ __launch_bounds__(256) void prep_kernel(
    const float* __restrict__ src, unsigned short* __restrict__ dst,
    int ntiles, int nrows)
{
    const int idx = blockIdx.x * 256 + threadIdx.x;
    if (idx >= ntiles * 4 * 128) return;
    const int r    = idx & 127;
    const int c    = idx >> 7;
    const int cs   = c & 3;
    const int tile = c >> 2;
    int row = tile * 128 + r; if (row > nrows - 1) row = nrows - 1;
    const float* s = src + (size_t)row * GH + (cs & 1) * 64;
    unsigned short* d = dst + (size_t)c * 8192 + r * 64;
    const bool lo = (cs >= 2);
    const int rx = r & 7;

    #pragma unroll
    for (int gq = 0; gq < 8; ++gq) {
        float x[8];
        *(float4*)(x)     = *(const float4*)(s + gq * 8);
        *(float4*)(x + 4) = *(const float4*)(s + gq * 8 + 4);
        unsigned u[4];
        #pragma unroll
        for (int q = 0; q < 4; ++q) {
            const float a0 = x[q * 2], a1 = x[q * 2 + 1];
            const unsigned short hi0 = f2bf(a0), hi1 = f2bf(a1);
            unsigned short h0, h1;
            if (lo) { h0 = f2bf(a0 - bf2f(hi0)); h1 = f2bf(a1 - bf2f(hi1)); }
            else    { h0 = hi0; h1 = hi1; }
            u[q] = (unsigned)h0 | ((unsigned)h1 << 16);
        }
        *(uint4*)(d + (size_t)((gq ^ rx) * 8)) = *(const uint4*)u;
    }
}

// ---------------------------------------------------------------------------
// Kernel 3: MFMA logits GEMM, K=384 bf16 (hi*hi + hi*lo + lo*hi), 128x128
// tile, 4 waves, single-buffered, m-fastest grid (r5 base = best).
// SINGLE change vs r5: minimum-staging K-step order. The 6 chunk-products
// are walked so consecutive steps share a chunk; each unique chunk (4 of A,
// 4 of W) is staged EXACTLY ONCE -> 8 stages = 128 KB/block vs r5's 12
// stages = 192 KB (-33% L2->LDS traffic, the r5-r7 experiments' surviving
// bottleneck). Chunk ids: 0=hi k0..63, 1=hi k64..127, 2=lo k0..63, 3=lo k64+.
//   s:        0        1        2        3        4        5
//   prod:  Ah0*Wl0  Ah0*Wh0  Al0*Wh0  Ah1*Wl1  Ah1*Wh1  Al1*Wh1
//   stage:  A0,W2     W0       A2      A1,W3     W1       A3
// ---------------------------------------------------------------------------
__global__ __launch_bounds__(256) void mfma_logits_kernel(
    const unsigned short* __restrict__ Ap, const unsigned short* __restrict__ Wp,
    const float* __restrict__ bias,
    float* __restrict__ logits, float* __restrict__ pmax, float* __restrict__ psum)
{
    __shared__ unsigned short ldsA[8192];
    __shared__ unsigned short ldsW[8192];
    __shared__ float sM[2][128];
    __shared__ float sS[2][128];

    const int bm  = blockIdx.x;     // m tile (fastest -> W-tile L2 locality)
    const int bt  = blockIdx.y;     // n tile
    const int tid = threadIdx.x;
    const int wid  = tid >> 6;
    const int lane = tid & 63;
    const int wm = wid >> 1, wn = wid & 1;
    const int l15 = lane & 15, l4 = lane >> 4;

    // minimum-staging walk (see header comment)
    constexpr int amap[6] = {0, 0, 2, 1, 1, 3};
    constexpr int astg[6] = {1, 0, 1, 1, 0, 1};
    constexpr int wmap[6] = {2, 0, 0, 3, 1, 1};
    constexpr int wstg[6] = {1, 1, 0, 1, 1, 0};

    f32x4 acc[4][4];
    #pragma unroll
    for (int i = 0; i < 4; ++i)
        #pragma unroll
        for (int j = 0; j < 4; ++j) acc[i][j] = (f32x4){0.f, 0.f, 0.f, 0.f};

    #pragma unroll
    for (int s = 0; s < 6; ++s) {
        if (astg[s]) {
            const unsigned short* ga = Ap + (size_t)(bm * 4 + amap[s]) * 8192 + wid * 2048 + lane * 8;
            #pragma unroll
            for (int i = 0; i < 4; ++i)
                __builtin_amdgcn_global_load_lds(
                    (const __attribute__((address_space(1))) void*)(ga + i * 512),
                    (__attribute__((address_space(3))) void*)(&ldsA[wid * 2048 + i * 512]), 16, 0, 0);
        }
        if (wstg[s]) {
            const unsigned short* gw = Wp + (size_t)(bt * 4 + wmap[s]) * 8192 + wid * 2048 + lane * 8;
            #pragma unroll
            for (int i = 0; i < 4; ++i)
                __builtin_amdgcn_global_load_lds(
                    (const __attribute__((address_space(1))) void*)(gw + i * 512),
                    (__attribute__((address_space(3))) void*)(&ldsW[wid * 2048 + i * 512]), 16, 0, 0);
        }
        __syncthreads();   // drains vmcnt before barrier -> LDS image complete

        #pragma unroll
        for (int ks = 0; ks < 2; ++ks) {
            bf16x8 af[4], bf[4];
            #pragma unroll
            for (int mi = 0; mi < 4; ++mi) {
                const int row = wm * 64 + mi * 16 + l15;
                const int off = row * 64 + ((ks * 32 + l4 * 8) ^ ((row & 7) << 3));
                af[mi] = *(const bf16x8*)&ldsA[off];
            }
            #pragma unroll
            for (int nj = 0; nj < 4; ++nj) {
                const int row = wn * 64 + nj * 16 + l15;
                const int off = row * 64 + ((ks * 32 + l4 * 8) ^ ((row & 7) << 3));
                bf[nj] = *(const bf16x8*)&ldsW[off];
            }
            #pragma unroll
            for (int mi = 0; mi < 4; ++mi)
                #pragma unroll
                for (int nj = 0; nj < 4; ++nj)
                    acc[mi][nj] = __builtin_amdgcn_mfma_f32_16x16x32_bf16(
                        af[mi], bf[nj], acc[mi][nj], 0, 0, 0);
        }
        __syncthreads();   // protect LDS before next stage overwrites
    }

    // ---- epilogue: bias, store, per-(row, tile) softmax partials ----
    float bj[4]; bool nv[4];
    #pragma unroll
    for (int nj = 0; nj < 4; ++nj) {
        const int n = bt * 128 + wn * 64 + nj * 16 + l15;
        nv[nj] = (n < GV);
        bj[nj] = nv[nj] ? bias[n] : 0.f;
    }
    #pragma unroll
    for (int mi = 0; mi < 4; ++mi) {
        #pragma unroll
        for (int r = 0; r < 4; ++r) {
            const int rowb = wm * 64 + mi * 16 + l4 * 4 + r;
            const int m = bm * 128 + rowb;
            float v[4];
            #pragma unroll
            for (int nj = 0; nj < 4; ++nj) v[nj] = acc[mi][nj][r] + bj[nj];
            if (m < GM) {
                #pragma unroll
                for (int nj = 0; nj < 4; ++nj)
                    if (nv[nj])
                        logits[(size_t)m * GV + (bt * 128 + wn * 64 + nj * 16 + l15)] = v[nj];
            }
            float mx = -INFINITY;
            #pragma unroll
            for (int nj = 0; nj < 4; ++nj) if (nv[nj]) mx = fmaxf(mx, v[nj]);
            #pragma unroll
            for (int d = 1; d < 16; d <<= 1) mx = fmaxf(mx, __shfl_xor(mx, d));
            float se = 0.f;
            #pragma unroll
            for (int nj = 0; nj < 4; ++nj) if (nv[nj]) se += __expf(v[nj] - mx);
            #pragma unroll
            for (int d = 1; d < 16; d <<= 1) se += __shfl_xor(se, d);
            if (l15 == 0) { sM[wn][rowb] = mx; sS[wn][rowb] = se; }
        }
    }
    __syncthreads();
    if (tid < 128) {
        const int m = bm * 128 + tid;
        if (m < GM) {
            const float m0 = sM[0][tid], m1 = sM[1][tid];
            const float M = fmaxf(m0, m1);
            const float S = sS[0][tid] * __expf(m0 - M) + sS[1][tid] * __expf(m1 - M);
            pmax[(size_t)m * NT + bt] = M;
            psum[(size_t)m * NT + bt] = S;
        }
    }
}

// ---------------------------------------------------------------------------
// Kernel 4: merge per-tile (max,sum) -> per-row (max, 1/sum). 1 wave per row.
// ---------------------------------------------------------------------------
__global__ __launch_bounds__(64) void reduce_kernel(
    const float* __restrict__ pmax, const float* __restrict__ psum,
    float* __restrict__ rowM, float* __restrict__ rowInvS)
{
    const int m = blockIdx.x;
    const int lane = threadIdx.x;
    float M = -INFINITY, S = 0.f;
    for (int t = lane; t < NT; t += 64) {
        const float m2 = pmax[(size_t)m * NT + t];
        const float s2 = psum[(size_t)m * NT + t];
        const float nM = fmaxf(M, m2);
        S = S * expf(M - nM) + s2 * expf(m2 - nM);
        M = nM;
    }
    #pragma unroll
    for (int d = 1; d < 64; d <<= 1) {
        const float m2 = __shfl_xor(M, d);
        const float s2 = __shfl_xor(S, d);
        const float nM = fmaxf(M, m2);
        S = S * expf(M - nM) + s2 * expf(m2 - nM);
        M = nM;
    }
    if (lane == 0) { rowM[m] = M; rowInvS[m] = 1.f / S; }
}

// ---------------------------------------------------------------------------
// Kernel 5: probs = exp(logits - M) * invS. float4 grid-stride.
// ---------------------------------------------------------------------------
__global__ __launch_bounds__(256) void probs_kernel(
    const float* __restrict__ logits,
    const float* __restrict__ rowM, const float* __restrict__ rowInvS,
    float* __restrict__ probs)
{
    const float4* L4 = reinterpret_cast<const float4*>(logits);
    float4* P4 = reinterpret_cast<float4*>(probs);
    const int n4 = (int)(((long long)GM * GV) / 4);
    const int stride = gridDim.x * blockDim.x;
    for (int i = blockIdx.x * blockDim.x + threadIdx.x; i < n4; i += stride) {
        const float4 v = L4[i];
        const int base = i * 4;
        const int m0 = base / GV;
        const int m3 = (base + 3) / GV;
        float4 o;
        if (m0 == m3) {
            const float M = rowM[m0], Is = rowInvS[m0];
            o.x = __expf(v.x - M) * Is;
            o.y = __expf(v.y - M) * Is;
            o.z = __expf(v.z - M) * Is;
            o.w = __expf(v.w - M) * Is;
        } else {
            const int ma = base / GV, mb = (base + 1) / GV;
            const int mc = (base + 2) / GV, md = (base + 3) / GV;
            o.x = __expf(v.x - rowM[ma]) * rowInvS[ma];
            o.y = __expf(v.y - rowM[mb]) * rowInvS[mb];
            o.z = __expf(v.z - rowM[mc]) * rowInvS[mc];
            o.w = __expf(v.w - rowM[md]) * rowInvS[md];
        }
        P4[i] = o;
    }
}

// ---------------------------------------------------------------------------
extern "C" void kernel_launch(void* const* d_in, const int* in_sizes, int n_in,
                              void* d_out, int out_size, void* d_ws, size_t ws_size,
                              hipStream_t stream) {
    const int*   tok    = (const int*)d_in[0];
    const float* emb    = (const float*)d_in[1];
    const float* gate_k = (const float*)d_in[2];
    const float* gate_b = (const float*)d_in[3];
    const float* cand_k = (const float*)d_in[4];
    const float* cand_b = (const float*)d_in[5];
    const float* W      = (const float*)d_in[6];
    const float* bias   = (const float*)d_in[7];

    float* logits = (float*)d_out;
    float* probs  = logits + (size_t)GM * GV;

    float* ws = (float*)d_ws;
    float* gruout = ws;                                        // 640,000 f32
    unsigned short* Ap = (unsigned short*)(gruout + 640000);   // 40*4*8192 bf16
    unsigned short* Wp = Ap + (size_t)MT * 4 * 8192;           // 393*4*8192 bf16
    float* pmax    = (float*)(Wp + (size_t)NT * 4 * 8192);
    float* psum    = pmax + (size_t)GM * NT;
    float* rowM    = psum + (size_t)GM * NT;
    float* rowInvS = rowM + GM;

    gru_kernel<<<GB, 1024, 0, stream>>>(tok, emb, gate_k, gate_b, cand_k, cand_b, gruout);

    prep_kernel<<<(MT * 4 * 128 + 255) / 256, 256, 0, stream>>>(gruout, Ap, MT, GM);
    prep_kernel<<<(NT * 4 * 128 + 255) / 256, 256, 0, stream>>>(W, Wp, NT, GV);

    dim3 g2(MT, NT);   // m-tile fastest: W-tile L2/L3 locality
    mfma_logits_kernel<<<g2, 256, 0, stream>>>(Ap, Wp, bias, logits, pmax, psum);

    reduce_kernel<<<GM, 64, 0, stream>>>(pmax, psum, rowM, rowInvS);

    probs_kernel<<<4096, 256, 0, stream>>>(logits, rowM, rowInvS, probs);
}